// Round 3
// baseline (260.863 us; speedup 1.0000x reference)
//
#include <hip/hip_runtime.h>

// Pipeline is fully linear in `project`:
//   out[n,k] = <Cmat[k], project[n]> + d[k]
// Cmat = spread(w_head) · (w3·w2·w1);  d = bh + spread-fold of composed biases.
//
// ws layout (floats):
//   A0    [1960][512]   spread(wh), row = k*196+hw     off 0
//   W23   [512][512]    w3·w2                          off 1003520
//   W123  [512][512]    W23·w1                         off 1265664
//   Cmat  [10][c*196+hw] A0·W123, transposed epilogue  off 1527808
//   vvec  [512]         composed channel bias          off 2531328
//   dvec  [16]          per-output bias                off 2531840
//   part  [32][512][10] k_main segment partials        off 2531856

#define CHW 100352   // 512*196
#define STEP 1.8571428571428572f  // 13/7

__device__ __forceinline__ float edge_w(int p, float s, int lim) {
    float f = floorf(s);
    float wfrac = s - f;
    int a = (int)f;
    int b = a + 1;
    a = min(max(a, 0), lim); b = min(max(b, 0), lim);
    float c = 0.f;
    if (p == a) c += 1.f - wfrac;
    if (p == b) c += wfrac;
    return c;
}

// A0[k*196+hw][o] = sum_{j,i} wh[k][o*49 + j*7+i] * cy(j,h) * cx(i,w)
__global__ void k_spread(const float* __restrict__ w_note,
                         const float* __restrict__ w_reg,
                         float* __restrict__ A0) {
    int tid = blockIdx.x * 256 + threadIdx.x;
    int o  = tid & 511;
    int hw = (tid >> 9) % 196;
    int k  = tid / CHW;
    int h = hw / 14, w = hw % 14;
    const float* wh = (k < 2) ? (w_note + k * 25088) : (w_reg + (k - 2) * 25088);
    const float base = STEP * 0.5f - 0.5f;
    float acc = 0.f;
    for (int j = 0; j < 7; ++j) {
        float cy = edge_w(h, base + j * STEP, 13);
        if (cy == 0.f) continue;
        for (int i = 0; i < 7; ++i) {
            float cx = edge_w(w, base + i * STEP, 13);
            if (cx != 0.f) acc += cy * cx * wh[o * 49 + j * 7 + i];
        }
    }
    A0[tid] = acc;
}

// C[M x 512] = A[M x 512] · B[512 x 512]; 64x64 tiles, thread = 4x4.
// OUT_MODE 0: row-major C.  OUT_MODE 1: row r=k*196+hw -> C[k*CHW + c*196 + hw].
template <int OUT_MODE>
__global__ __launch_bounds__(256) void k_mm(const float* __restrict__ A,
                                            const float* __restrict__ B,
                                            float* __restrict__ C, int M) {
    __shared__ __align__(16) float As[16][68];
    __shared__ __align__(16) float Bs[16][68];
    int bx = blockIdx.x, by = blockIdx.y;
    int tid = threadIdx.x;
    int tx = tid & 15, ty = tid >> 4;
    int akk = tid & 15, arow = tid >> 4;
    int bcol = tid & 63, bkr = tid >> 6;
    float acc[4][4];
    #pragma unroll
    for (int i = 0; i < 4; ++i)
        #pragma unroll
        for (int j = 0; j < 4; ++j) acc[i][j] = 0.f;

    for (int ks = 0; ks < 32; ++ks) {
        #pragma unroll
        for (int p = 0; p < 4; ++p) {
            int gr = by * 64 + arow + p * 16;
            As[akk][arow + p * 16] = (gr < M) ? A[(size_t)gr * 512 + ks * 16 + akk] : 0.f;
        }
        #pragma unroll
        for (int p = 0; p < 4; ++p) {
            int kr = bkr + p * 4;
            Bs[kr][bcol] = B[(size_t)(ks * 16 + kr) * 512 + bx * 64 + bcol];
        }
        __syncthreads();
        #pragma unroll
        for (int kk = 0; kk < 16; ++kk) {
            float4 a = *(const float4*)&As[kk][ty * 4];
            float4 b = *(const float4*)&Bs[kk][tx * 4];
            acc[0][0] += a.x * b.x; acc[0][1] += a.x * b.y; acc[0][2] += a.x * b.z; acc[0][3] += a.x * b.w;
            acc[1][0] += a.y * b.x; acc[1][1] += a.y * b.y; acc[1][2] += a.y * b.z; acc[1][3] += a.y * b.w;
            acc[2][0] += a.z * b.x; acc[2][1] += a.z * b.y; acc[2][2] += a.z * b.z; acc[2][3] += a.z * b.w;
            acc[3][0] += a.w * b.x; acc[3][1] += a.w * b.y; acc[3][2] += a.w * b.z; acc[3][3] += a.w * b.w;
        }
        __syncthreads();
    }
    #pragma unroll
    for (int i = 0; i < 4; ++i) {
        int r = by * 64 + ty * 4 + i;
        if (r < M) {
            if (OUT_MODE == 0) {
                float4 v = make_float4(acc[i][0], acc[i][1], acc[i][2], acc[i][3]);
                *(float4*)&C[(size_t)r * 512 + bx * 64 + tx * 4] = v;
            } else {
                int k = r / 196, hw = r - k * 196;
                int c0 = bx * 64 + tx * 4;
                #pragma unroll
                for (int j = 0; j < 4; ++j)
                    C[(size_t)k * CHW + (c0 + j) * 196 + hw] = acc[i][j];
            }
        }
    }
}

// vvec[o] = b3[o] + sum_l w3[o][l]*b2[l] + sum_l W23[o][l]*b1[l]
__global__ void k_bvec(const float* __restrict__ w3, const float* __restrict__ W23,
                       const float* __restrict__ b1, const float* __restrict__ b2,
                       const float* __restrict__ b3, float* __restrict__ vvec) {
    int o = blockIdx.x;
    int l = threadIdx.x;  // 64
    float s = 0.f;
    for (int i = l; i < 512; i += 64)
        s += w3[o * 512 + i] * b2[i] + W23[o * 512 + i] * b1[i];
    for (int off = 32; off; off >>= 1) s += __shfl_down(s, off);
    if (l == 0) vvec[o] = b3[o] + s;
}

// dvec[k] = bh[k] + sum_i wh[k][i] * vvec[i/49]
__global__ void k_dvec(const float* __restrict__ w_note, const float* __restrict__ w_reg,
                       const float* __restrict__ b_note, const float* __restrict__ b_reg,
                       const float* __restrict__ vvec, float* __restrict__ dvec) {
    int k = blockIdx.x;
    int t = threadIdx.x;  // 256
    const float* wh = (k < 2) ? (w_note + k * 25088) : (w_reg + (k - 2) * 25088);
    float s = 0.f;
    for (int i = t; i < 25088; i += 256) s += wh[i] * vvec[i / 49];
    __shared__ float red[256];
    red[t] = s;
    __syncthreads();
    for (int off = 128; off; off >>= 1) {
        if (t < off) red[t] += red[t + off];
        __syncthreads();
    }
    if (t == 0) dvec[k] = red[0] + ((k < 2) ? b_note[k] : b_reg[k - 2]);
}

// partials[s][n][k] = sum over segment s of Cmat[k]·project[n]
// Software-pipelined: next iter's 11 float4 loads issued before current FMAs.
__global__ __launch_bounds__(256) void k_main(const float* __restrict__ proj,
                                              const float* __restrict__ Cmat,
                                              float* __restrict__ partials) {
    int s = blockIdx.x;   // 32 segments of 3136 chw
    int g = blockIdx.y;   // 32 groups of 16 n
    int tid = threadIdx.x;
    int nl = tid >> 4, t = tid & 15;
    int n = g * 16 + nl;
    const float* pn = proj + (size_t)n * CHW + s * 3136 + t * 4;
    const float* cb = Cmat + s * 3136 + t * 4;
    float acc[10];
    #pragma unroll
    for (int k = 0; k < 10; ++k) acc[k] = 0.f;

    float4 p = *(const float4*)pn;
    float4 cm[10];
    #pragma unroll
    for (int k = 0; k < 10; ++k) cm[k] = *(const float4*)(cb + (size_t)k * CHW);

    #pragma unroll 2
    for (int it = 0; it < 48; ++it) {
        float4 p2 = *(const float4*)(pn + (it + 1) * 64);
        float4 cm2[10];
        #pragma unroll
        for (int k = 0; k < 10; ++k)
            cm2[k] = *(const float4*)(cb + (size_t)k * CHW + (it + 1) * 64);
        #pragma unroll
        for (int k = 0; k < 10; ++k)
            acc[k] += p.x * cm[k].x + p.y * cm[k].y + p.z * cm[k].z + p.w * cm[k].w;
        p = p2;
        #pragma unroll
        for (int k = 0; k < 10; ++k) cm[k] = cm2[k];
    }
    #pragma unroll
    for (int k = 0; k < 10; ++k)
        acc[k] += p.x * cm[k].x + p.y * cm[k].y + p.z * cm[k].z + p.w * cm[k].w;

    #pragma unroll
    for (int k = 0; k < 10; ++k) {
        float v = acc[k];
        v += __shfl_xor(v, 1, 16);
        v += __shfl_xor(v, 2, 16);
        v += __shfl_xor(v, 4, 16);
        v += __shfl_xor(v, 8, 16);
        if (t == 0) partials[(s * 512 + n) * 10 + k] = v;
    }
}

__global__ void k_reduce(const float* __restrict__ partials,
                         const float* __restrict__ dvec,
                         float* __restrict__ out) {
    int idx = blockIdx.x * 256 + threadIdx.x;  // 0..5119
    int n = idx / 10, k = idx % 10;
    float s = dvec[k];
    for (int seg = 0; seg < 32; ++seg) s += partials[(seg * 512 + n) * 10 + k];
    if (k < 2) out[n * 2 + k] = s;
    else       out[1024 + n * 8 + (k - 2)] = s;
}

extern "C" void kernel_launch(void* const* d_in, const int* in_sizes, int n_in,
                              void* d_out, int out_size, void* d_ws, size_t ws_size,
                              hipStream_t stream) {
    const float* proj   = (const float*)d_in[0];
    const float* w1     = (const float*)d_in[1];
    const float* b1     = (const float*)d_in[2];
    const float* w2     = (const float*)d_in[3];
    const float* b2     = (const float*)d_in[4];
    const float* w3     = (const float*)d_in[5];
    const float* b3     = (const float*)d_in[6];
    const float* w_note = (const float*)d_in[7];
    const float* b_note = (const float*)d_in[8];
    const float* w_reg  = (const float*)d_in[9];
    const float* b_reg  = (const float*)d_in[10];

    float* ws   = (float*)d_ws;
    float* A0   = ws;
    float* W23  = A0 + 1003520;
    float* W123 = W23 + 262144;
    float* Cm   = W123 + 262144;
    float* vvec = Cm + 1003520;
    float* dvec = vvec + 512;
    float* part = dvec + 16;
    float* out  = (float*)d_out;

    k_mm<0><<<dim3(8, 8), 256, 0, stream>>>(w3, w2, W23, 512);
    k_mm<0><<<dim3(8, 8), 256, 0, stream>>>(W23, w1, W123, 512);
    k_spread<<<3920, 256, 0, stream>>>(w_note, w_reg, A0);
    k_mm<1><<<dim3(8, 31), 256, 0, stream>>>(A0, W123, Cm, 1960);
    k_bvec<<<512, 64, 0, stream>>>(w3, W23, b1, b2, b3, vvec);
    k_dvec<<<10, 256, 0, stream>>>(w_note, w_reg, b_note, b_reg, vvec, dvec);
    k_main<<<dim3(32, 32), 256, 0, stream>>>(proj, Cm, part);
    k_reduce<<<20, 256, 0, stream>>>(part, dvec, out);
}

// Round 4
// 160.194 us; speedup vs baseline: 1.6284x; 1.6284x over previous
//
#include <hip/hip_runtime.h>

// out[n,k] = <Cmat[k], project[n]> + d[k]   (pipeline is fully linear in project)
// Cmat[k][c*196+hw] = sum_ji R[ji,hw] * Bmat[(k,ji)][c],  Bmat = WH · (w3·w2·w1)
//
// ws layout (floats):
//   W23   [512][512]                off 0
//   W123  [512][512]                off 262144
//   WH    [490][512]                off 524288
//   Bmat  [490][512]                off 775168
//   Cmat  [10][c*196+hw]            off 1026048
//   vvec  [512]                     off 2029568
//   dpart [10][8]                   off 2030080
//   part  [8][512][10]              off 2030160

#define CHW 100352   // 512*196
#define SEG 12544    // CHW/8
#define STEP 1.8571428571428572f  // 13/7

__device__ __forceinline__ float edge_w(int p, float s, int lim) {
    float f = floorf(s);
    float wfrac = s - f;
    int a = (int)f;
    int b = a + 1;
    a = min(max(a, 0), lim); b = min(max(b, 0), lim);
    float c = 0.f;
    if (p == a) c += 1.f - wfrac;
    if (p == b) c += wfrac;
    return c;
}

// C[M x 512] = A[M x 512] * B[512 x 512]; 32x32 tile per block, thread = 2x2.
__global__ __launch_bounds__(256) void k_mm32(const float* __restrict__ A,
                                              const float* __restrict__ B,
                                              float* __restrict__ C, int M) {
    __shared__ float As[32][36];
    __shared__ float Bs[32][36];
    int bx = blockIdx.x, by = blockIdx.y;
    int tid = threadIdx.x;
    int lr = tid >> 3;          // 0..31
    int lc = (tid & 7) << 2;    // 0,4,..,28
    int tx = tid & 15, ty = tid >> 4;
    float a00 = 0.f, a01 = 0.f, a10 = 0.f, a11 = 0.f;
    for (int kc = 0; kc < 512; kc += 32) {
        int gr = by * 32 + lr;
        float4 av = make_float4(0.f, 0.f, 0.f, 0.f);
        if (gr < M) av = *(const float4*)&A[(size_t)gr * 512 + kc + lc];
        *(float4*)&As[lr][lc] = av;
        float4 bv = *(const float4*)&B[(size_t)(kc + lr) * 512 + bx * 32 + lc];
        *(float4*)&Bs[lr][lc] = bv;
        __syncthreads();
        #pragma unroll
        for (int kk = 0; kk < 32; ++kk) {
            float b0 = Bs[kk][tx * 2], b1 = Bs[kk][tx * 2 + 1];
            float x0 = As[ty * 2][kk], x1 = As[ty * 2 + 1][kk];
            a00 += x0 * b0; a01 += x0 * b1;
            a10 += x1 * b0; a11 += x1 * b1;
        }
        __syncthreads();
    }
    int r0 = by * 32 + ty * 2, c0 = bx * 32 + tx * 2;
    if (r0 < M)     { C[(size_t)r0 * 512 + c0] = a00; C[(size_t)r0 * 512 + c0 + 1] = a01; }
    if (r0 + 1 < M) { C[(size_t)(r0 + 1) * 512 + c0] = a10; C[(size_t)(r0 + 1) * 512 + c0 + 1] = a11; }
}

// WH[r][q] = wh[k][q*49 + ji],  r = k*49 + ji
__global__ void k_whT(const float* __restrict__ w_note, const float* __restrict__ w_reg,
                      float* __restrict__ WH) {
    int r = blockIdx.x;      // 0..489
    int q = threadIdx.x;     // 0..511
    int k = r / 49, ji = r % 49;
    const float* wh = (k < 2) ? (w_note + k * 25088) : (w_reg + (k - 2) * 25088);
    WH[(size_t)r * 512 + q] = wh[q * 49 + ji];
}

// Cm[k*CHW + c*196 + hw] = sum_ji cy(j,h)*cx(i,w) * Bmat[(k*49+ji)*512 + c]
__global__ void k_spread2(const float* __restrict__ Bmat, float* __restrict__ Cm) {
    int c = blockIdx.x;      // 0..511
    int k = blockIdx.y;      // 0..9
    int hw = threadIdx.x;    // 0..195
    int h = hw / 14, w = hw % 14;
    const float base = STEP * 0.5f - 0.5f;
    float acc = 0.f;
    for (int j = 0; j < 7; ++j) {
        float cy = edge_w(h, base + j * STEP, 13);
        if (cy == 0.f) continue;
        for (int i = 0; i < 7; ++i) {
            float cx = edge_w(w, base + i * STEP, 13);
            if (cx != 0.f) acc += cy * cx * Bmat[(size_t)(k * 49 + j * 7 + i) * 512 + c];
        }
    }
    Cm[(size_t)k * CHW + c * 196 + hw] = acc;
}

// vvec[q] = b3[q] + sum_p w3[q][p]*b2[p] + sum_o W23[q][o]*b1[o]
__global__ void k_bvec(const float* __restrict__ w3, const float* __restrict__ W23,
                       const float* __restrict__ b1, const float* __restrict__ b2,
                       const float* __restrict__ b3, float* __restrict__ vvec) {
    int o = blockIdx.x;
    int l = threadIdx.x;  // 64
    float s = 0.f;
    for (int i = l; i < 512; i += 64)
        s += w3[o * 512 + i] * b2[i] + W23[o * 512 + i] * b1[i];
    for (int off = 32; off; off >>= 1) s += __shfl_down(s, off);
    if (l == 0) vvec[o] = b3[o] + s;
}

// dpart[k][b] = partial of sum_i wh[k][i] * vvec[i/49]
__global__ void k_dvec(const float* __restrict__ w_note, const float* __restrict__ w_reg,
                       const float* __restrict__ vvec, float* __restrict__ dpart) {
    int k = blockIdx.x;   // 10
    int b = blockIdx.y;   // 8
    int t = threadIdx.x;  // 256
    const float* wh = (k < 2) ? (w_note + k * 25088) : (w_reg + (k - 2) * 25088);
    float s = 0.f;
    for (int i = b * 256 + t; i < 25088; i += 2048) s += wh[i] * vvec[i / 49];
    __shared__ float red[256];
    red[t] = s;
    __syncthreads();
    for (int off = 128; off; off >>= 1) {
        if (t < off) red[t] += red[t + off];
        __syncthreads();
    }
    if (t == 0) dpart[k * 8 + b] = red[0];
}

// One wave = one n: 64 lanes read 1KB contiguous per load (m13 copy pattern).
// grid (8 s, 128 g); block = 4 waves; wave w owns n = g*4 + w, chw in [s*SEG, s*SEG+SEG).
__global__ __launch_bounds__(256, 4) void k_main(const float* __restrict__ proj,
                                                 const float* __restrict__ Cmat,
                                                 float* __restrict__ part) {
    int s = blockIdx.x;
    int g = blockIdx.y;
    int wv = threadIdx.x >> 6;
    int lane = threadIdx.x & 63;
    int n = g * 4 + wv;
    const float* pn = proj + (size_t)n * CHW + s * SEG + lane * 4;
    const float* cb = Cmat + s * SEG + lane * 4;
    float acc[10];
    #pragma unroll
    for (int k = 0; k < 10; ++k) acc[k] = 0.f;

    float4 p = *(const float4*)pn;
    float4 cm[10];
    #pragma unroll
    for (int k = 0; k < 10; ++k) cm[k] = *(const float4*)(cb + (size_t)k * CHW);

    #pragma unroll 2
    for (int it = 0; it < 48; ++it) {
        float4 p2 = *(const float4*)(pn + (it + 1) * 256);
        float4 cm2[10];
        #pragma unroll
        for (int k = 0; k < 10; ++k)
            cm2[k] = *(const float4*)(cb + (size_t)k * CHW + (it + 1) * 256);
        #pragma unroll
        for (int k = 0; k < 10; ++k)
            acc[k] += p.x * cm[k].x + p.y * cm[k].y + p.z * cm[k].z + p.w * cm[k].w;
        p = p2;
        #pragma unroll
        for (int k = 0; k < 10; ++k) cm[k] = cm2[k];
    }
    #pragma unroll
    for (int k = 0; k < 10; ++k)
        acc[k] += p.x * cm[k].x + p.y * cm[k].y + p.z * cm[k].z + p.w * cm[k].w;

    #pragma unroll
    for (int k = 0; k < 10; ++k) {
        float v = acc[k];
        v += __shfl_xor(v, 1);
        v += __shfl_xor(v, 2);
        v += __shfl_xor(v, 4);
        v += __shfl_xor(v, 8);
        v += __shfl_xor(v, 16);
        v += __shfl_xor(v, 32);
        if (lane == 0) part[(s * 512 + n) * 10 + k] = v;
    }
}

__global__ void k_reduce(const float* __restrict__ part,
                         const float* __restrict__ dpart,
                         const float* __restrict__ b_note, const float* __restrict__ b_reg,
                         float* __restrict__ out) {
    int idx = blockIdx.x * 256 + threadIdx.x;  // 0..5119
    int n = idx / 10, k = idx % 10;
    float s = (k < 2) ? b_note[k] : b_reg[k - 2];
    for (int b = 0; b < 8; ++b) s += dpart[k * 8 + b];
    for (int seg = 0; seg < 8; ++seg) s += part[(seg * 512 + n) * 10 + k];
    if (k < 2) out[n * 2 + k] = s;
    else       out[1024 + n * 8 + (k - 2)] = s;
}

extern "C" void kernel_launch(void* const* d_in, const int* in_sizes, int n_in,
                              void* d_out, int out_size, void* d_ws, size_t ws_size,
                              hipStream_t stream) {
    const float* proj   = (const float*)d_in[0];
    const float* w1     = (const float*)d_in[1];
    const float* b1     = (const float*)d_in[2];
    const float* w2     = (const float*)d_in[3];
    const float* b2     = (const float*)d_in[4];
    const float* w3     = (const float*)d_in[5];
    const float* b3     = (const float*)d_in[6];
    const float* w_note = (const float*)d_in[7];
    const float* b_note = (const float*)d_in[8];
    const float* w_reg  = (const float*)d_in[9];
    const float* b_reg  = (const float*)d_in[10];

    float* ws    = (float*)d_ws;
    float* W23   = ws;
    float* W123  = W23 + 262144;
    float* WH    = W123 + 262144;
    float* Bmat  = WH + 250880;
    float* Cm    = Bmat + 250880;
    float* vvec  = Cm + 1003520;
    float* dpart = vvec + 512;
    float* part  = dpart + 80;
    float* out   = (float*)d_out;

    k_mm32<<<dim3(16, 16), 256, 0, stream>>>(w3, w2, W23, 512);
    k_mm32<<<dim3(16, 16), 256, 0, stream>>>(W23, w1, W123, 512);
    k_whT<<<490, 512, 0, stream>>>(w_note, w_reg, WH);
    k_mm32<<<dim3(16, 16), 256, 0, stream>>>(WH, W123, Bmat, 490);
    k_spread2<<<dim3(512, 10), 196, 0, stream>>>(Bmat, Cm);
    k_bvec<<<512, 64, 0, stream>>>(w3, W23, b1, b2, b3, vvec);
    k_dvec<<<dim3(10, 8), 256, 0, stream>>>(w_note, w_reg, vvec, dpart);
    k_main<<<dim3(8, 128), 256, 0, stream>>>(proj, Cm, part);
    k_reduce<<<20, 256, 0, stream>>>(part, dpart, b_note, b_reg, out);
}